// Round 7
// baseline (177.599 us; speedup 1.0000x reference)
//
#include <hip/hip_runtime.h>

// SimCLR fused pipeline, round 16.
// r15 post-mortem: halving sim's work (symmetry) changed NOTHING -> sim is
// stall-bound per block (~21600 cyc/block for ~2000 cyc of instructions),
// not work-bound. Cause: monolithic stage(64KB)->sync->compute structure at
// 2 blocks/CU = zero VMEM/compute overlap (lockstep phases, no TLP depth).
// r16: r14's full-matrix sim body (identical math/swizzle/psum/rowfin), but
// B-slice staged in 4x16KB chunks, double-buffered LDS (32KB total):
// issue chunk c+1 global loads -> regs BEFORE computing chunk c; ds_write
// after barrier (G15 async-split). LDS 64->32KB + launch_bounds(256,4)
// -> 4 blocks/CU. One variable changed vs r14.
// prep/gemm1/gemm2/row_finalize byte-identical to r14.

#define NB   4096
#define DIN  192
#define DHID 512
#define DOUT 128
#define N2   8192   // 2*NB
#define NSPLIT 32   // sim col-splits; 256 cols per block
#define SIM_ITERS 16

typedef short short8 __attribute__((ext_vector_type(8)));   // 8 bf16 (4 VGPRs)
typedef float floatx4 __attribute__((ext_vector_type(4)));  // MFMA C/D frag

__device__ inline float fast_exp2(float x) {
#if __has_builtin(__builtin_amdgcn_exp2f)
    return __builtin_amdgcn_exp2f(x);
#else
    return exp2f(x);
#endif
}

__device__ inline unsigned short bf16_rne(float x) {
    unsigned int u = __float_as_uint(x);
    return (unsigned short)((u + 0x7fffu + ((u >> 16) & 1u)) >> 16);
}

// ------- prep: convert W1,W2 -> bf16; block 160 zeros psumc/psqc/out -------
__global__ __launch_bounds__(256) void prep(
    const float* __restrict__ W1, const float* __restrict__ W2,
    unsigned short* __restrict__ W1b, unsigned short* __restrict__ W2b,
    float* __restrict__ psumc, float* __restrict__ psqc, float* __restrict__ out)
{
    const int NW1 = DHID * DIN / 4;   // 24576 float4
    const int NW2 = DOUT * DHID / 4;  // 16384 float4
    if (blockIdx.x == 160) {          // zero accumulators
        int t = threadIdx.x;
        for (int i = t; i < 1024; i += 256) { psumc[i] = 0.f; psqc[i] = 0.f; }
        if (t == 0) out[0] = 0.f;
        return;
    }
    int id = blockIdx.x * 256 + threadIdx.x;
    const float* src; unsigned short* dst; int off;
    if (id < NW1)            { src = W1; dst = W1b; off = id; }
    else if (id < NW1 + NW2) { src = W2; dst = W2b; off = id - NW1; }
    else return;
    float4 x = ((const float4*)src)[off];
    unsigned int p0 = bf16_rne(x.x) | ((unsigned int)bf16_rne(x.y) << 16);
    unsigned int p1 = bf16_rne(x.z) | ((unsigned int)bf16_rne(x.w) << 16);
    ((uint2*)dst)[off] = make_uint2(p0, p1);
}

// ------- GEMM1 (r12, unchanged): Y = [h1;h2] @ W1^T + b1, fused BN sums ----
__global__ __launch_bounds__(256) void gemm1_mfma(
    const float* __restrict__ h1, const float* __restrict__ h2,
    const unsigned short* __restrict__ W1b, const float* __restrict__ b1,
    float* __restrict__ Y, float* __restrict__ psumc, float* __restrict__ psqc)
{
    const int t = threadIdx.x;
    const int wave = t >> 6, lane = t & 63;
    const int quad = lane >> 4, l15 = lane & 15;
    const int mb = blockIdx.x;
    const int m0 = mb * 128 + wave * 32;
    const int n0 = blockIdx.y * 64;
    const int v  = (mb >= 32);

    short8 a[2][6];
    #pragma unroll
    for (int mt = 0; mt < 2; ++mt) {
        int row = m0 + mt * 16 + l15;
        const float* hsrc = (row < NB) ? (h1 + (size_t)row * DIN)
                                       : (h2 + (size_t)(row - NB) * DIN);
        #pragma unroll
        for (int kc = 0; kc < 6; ++kc) {
            const float4* p = (const float4*)(hsrc + kc * 32 + quad * 8);
            float4 x0 = p[0], x1 = p[1];
            float xs[8] = {x0.x,x0.y,x0.z,x0.w,x1.x,x1.y,x1.z,x1.w};
            #pragma unroll
            for (int j = 0; j < 8; ++j) a[mt][kc][j] = (short)bf16_rne(xs[j]);
        }
    }

    #pragma unroll
    for (int nt = 0; nt < 4; ++nt) {
        const int col = n0 + nt * 16 + l15;
        const short8* bptr = (const short8*)(W1b + (size_t)col * DIN + quad * 8);
        short8 b[6];
        #pragma unroll
        for (int kc = 0; kc < 6; ++kc) b[kc] = bptr[kc * 4];
        floatx4 acc[2] = {{0.f,0.f,0.f,0.f},{0.f,0.f,0.f,0.f}};
        #pragma unroll
        for (int kc = 0; kc < 6; ++kc)
            #pragma unroll
            for (int mt = 0; mt < 2; ++mt)
                acc[mt] = __builtin_amdgcn_mfma_f32_16x16x32_bf16(a[mt][kc], b[kc], acc[mt], 0,0,0);
        const float bias = b1[col];
        float cs = 0.f, cq = 0.f;
        #pragma unroll
        for (int mt = 0; mt < 2; ++mt)
            #pragma unroll
            for (int reg = 0; reg < 4; ++reg) {
                float y = acc[mt][reg] + bias;
                int row = m0 + mt * 16 + quad * 4 + reg;
                Y[(size_t)row * DHID + col] = y;
                cs += y; cq += y * y;
            }
        cs += __shfl_xor(cs, 16); cs += __shfl_xor(cs, 32);
        cq += __shfl_xor(cq, 16); cq += __shfl_xor(cq, 32);
        if (quad == 0) {
            atomicAdd(psumc + v * DHID + col, cs);
            atomicAdd(psqc  + v * DHID + col, cq);
        }
    }
}

#define ZSCALE 1.6986436f   // sqrt(2*log2(e)); Zb = z*ZSCALE so dot = exp2 arg

// ---- GEMM2 (r12, unchanged): z = relu(bn(Y)) @ W2^T + b2, L2-norm ---------
__global__ __launch_bounds__(256) void gemm2_mfma(
    const float* __restrict__ Y, const unsigned short* __restrict__ W2b,
    const float* __restrict__ psumc, const float* __restrict__ psqc,
    const float* __restrict__ gamma, const float* __restrict__ beta,
    const float* __restrict__ b2,
    unsigned short* __restrict__ Zb, float* __restrict__ outz)
{
    __shared__ float sc_sh[DHID], sh_sh[DHID];
    __shared__ float sq_lds[4][16];
    const int t = threadIdx.x;
    const int wave = t >> 6, lane = t & 63;
    const int quad = lane >> 4, l15 = lane & 15;
    const int mtbase = blockIdx.x * 16;
    const int v = (mtbase >= NB);

    for (int c = t; c < DHID; c += 256) {
        float mean = psumc[v * DHID + c] * (1.0f / NB);
        float var  = psqc [v * DHID + c] * (1.0f / NB) - mean * mean;
        float rstd = rsqrtf(var + 1e-5f);
        float scv = gamma[c] * rstd;
        sc_sh[c] = scv;
        sh_sh[c] = beta[c] - mean * scv;
    }
    __syncthreads();

    const float* yrow = Y + (size_t)(mtbase + l15) * DHID;
    floatx4 acc[2] = {{0.f,0.f,0.f,0.f},{0.f,0.f,0.f,0.f}};
    for (int kc = 0; kc < 16; ++kc) {
        const int k = kc * 32 + quad * 8;
        float4 y0 = *(const float4*)(yrow + k);
        float4 y1 = *(const float4*)(yrow + k + 4);
        float4 s0 = *(const float4*)&sc_sh[k], s1 = *(const float4*)&sc_sh[k + 4];
        float4 h0 = *(const float4*)&sh_sh[k], h1v = *(const float4*)&sh_sh[k + 4];
        float xs[8];
        xs[0] = fmaxf(y0.x * s0.x + h0.x, 0.f);
        xs[1] = fmaxf(y0.y * s0.y + h0.y, 0.f);
        xs[2] = fmaxf(y0.z * s0.z + h0.z, 0.f);
        xs[3] = fmaxf(y0.w * s0.w + h0.w, 0.f);
        xs[4] = fmaxf(y1.x * s1.x + h1v.x, 0.f);
        xs[5] = fmaxf(y1.y * s1.y + h1v.y, 0.f);
        xs[6] = fmaxf(y1.z * s1.z + h1v.z, 0.f);
        xs[7] = fmaxf(y1.w * s1.w + h1v.w, 0.f);
        short8 a;
        #pragma unroll
        for (int j = 0; j < 8; ++j) a[j] = (short)bf16_rne(xs[j]);
        #pragma unroll
        for (int nt = 0; nt < 2; ++nt) {
            const int col = wave * 32 + nt * 16 + l15;
            short8 b = *(const short8*)(W2b + (size_t)col * DHID + k);
            acc[nt] = __builtin_amdgcn_mfma_f32_16x16x32_bf16(a, b, acc[nt], 0,0,0);
        }
    }
    float bias[2];
    #pragma unroll
    for (int nt = 0; nt < 2; ++nt) bias[nt] = b2[wave * 32 + nt * 16 + l15];

    float zv[4][2];
    #pragma unroll
    for (int reg = 0; reg < 4; ++reg) {
        float sq = 0.f;
        #pragma unroll
        for (int nt = 0; nt < 2; ++nt) {
            zv[reg][nt] = acc[nt][reg] + bias[nt];
            sq += zv[reg][nt] * zv[reg][nt];
        }
        sq += __shfl_xor(sq, 1); sq += __shfl_xor(sq, 2);
        sq += __shfl_xor(sq, 4); sq += __shfl_xor(sq, 8);
        if (l15 == 0) sq_lds[wave][quad * 4 + reg] = sq;
    }
    __syncthreads();
    #pragma unroll
    for (int reg = 0; reg < 4; ++reg) {
        float tot = sq_lds[0][quad * 4 + reg] + sq_lds[1][quad * 4 + reg]
                  + sq_lds[2][quad * 4 + reg] + sq_lds[3][quad * 4 + reg];
        float inv = 1.0f / fmaxf(sqrtf(tot), 1e-12f);
        const int row = mtbase + quad * 4 + reg;
        const size_t ob = (size_t)row * DOUT;
        #pragma unroll
        for (int nt = 0; nt < 2; ++nt) {
            const int col = wave * 32 + nt * 16 + l15;
            float z = zv[reg][nt] * inv;
            outz[ob + col] = z;
            Zb[ob + col] = bf16_rne(z * ZSCALE);
        }
    }
}

// ---- sim v4: r12 math, chunked double-buffered staging ---------------------
// 256-col slice staged as 4 chunks of 64 cols (16 KB), LDS dbuf [2][16KB].
// Per chunk: issue next chunk's 4 global loads -> regs, compute 4 iters from
// current buffer, barrier, ds_write prefetched regs, barrier. Staging hides
// under compute; 32 KB LDS -> 4 blocks/CU (launch_bounds(256,4)).
// grid (64, NSPLIT) x 256 thr.
__global__ __launch_bounds__(256, 4) void sim_mfma(
    const unsigned short* __restrict__ Zb, float* __restrict__ psum)
{
    __shared__ unsigned char bsh[2][16384];   // 2 x (64 rows x 256 B), swizzled
    const int t = threadIdx.x;
    const int wave = t >> 6, lane = t & 63;
    const int quad = lane >> 4, l15 = lane & 15;
    const int mbase = blockIdx.x * 128 + wave * 32;   // 32 rows per wave
    const int cs = blockIdx.y;                        // 0..NSPLIT-1
    const int cbase = cs * (N2 / NSPLIT);             // 256-col slice

    // A fragments: 32 rows per wave, K=128 (4 kc), kept in regs (issue first)
    short8 a[2][4];
    #pragma unroll
    for (int at = 0; at < 2; ++at) {
        const short8* zra = (const short8*)(Zb + (size_t)(mbase + at * 16 + l15) * DOUT + quad * 8);
        #pragma unroll
        for (int kc = 0; kc < 4; ++kc) a[at][kc] = zra[kc * 4];
    }

    // stage chunk 0 (rows cbase..cbase+63): 1024 uint4, 4 per thread
    {
        const uint4* src = (const uint4*)(Zb + (size_t)cbase * DOUT);
        #pragma unroll
        for (int k = 0; k < 4; ++k) {
            int idx = t + k * 256;            // uint4 index 0..1023
            uint4 vv = src[idx];
            int lr  = idx >> 4;               // local row 0..63
            int slot = idx & 15;              // 16B slot within row
            *(uint4*)(&bsh[0][lr * 256 + ((slot ^ (lr & 15)) << 4)]) = vv;
        }
    }

    float rs[2][4];
    #pragma unroll
    for (int at = 0; at < 2; ++at)
        #pragma unroll
        for (int r = 0; r < 4; ++r) rs[at][r] = 0.f;

    __syncthreads();   // chunk 0 staged

    #pragma unroll
    for (int c = 0; c < 4; ++c) {
        // issue next chunk's loads early (regs); written to LDS after barrier
        uint4 pre[4];
        if (c < 3) {
            const uint4* src = (const uint4*)(Zb + (size_t)(cbase + (c + 1) * 64) * DOUT);
            #pragma unroll
            for (int k = 0; k < 4; ++k) pre[k] = src[t + k * 256];
        }

        // compute 4 iterations from current buffer
        #pragma unroll
        for (int i = 0; i < 4; ++i) {
            const int lr = i * 16 + l15;      // local row in chunk
            short8 b[4];
            #pragma unroll
            for (int kc = 0; kc < 4; ++kc) {
                int slot = kc * 4 + quad;
                b[kc] = *(const short8*)(&bsh[c & 1][lr * 256 + ((slot ^ (lr & 15)) << 4)]);
            }
            floatx4 acc[2] = {{0.f,0.f,0.f,0.f},{0.f,0.f,0.f,0.f}};
            #pragma unroll
            for (int kc = 0; kc < 4; ++kc)
                #pragma unroll
                for (int at = 0; at < 2; ++at)
                    acc[at] = __builtin_amdgcn_mfma_f32_16x16x32_bf16(a[at][kc], b[kc], acc[at], 0, 0, 0);
            #pragma unroll
            for (int at = 0; at < 2; ++at)
                #pragma unroll
                for (int r = 0; r < 4; ++r)
                    rs[at][r] += fast_exp2(acc[at][r]);
        }

        if (c < 3) {
            __syncthreads();   // prior readers of the other buffer are done
            #pragma unroll
            for (int k = 0; k < 4; ++k) {
                int idx = t + k * 256;
                int lr  = idx >> 4;
                int slot = idx & 15;
                *(uint4*)(&bsh[(c + 1) & 1][lr * 256 + ((slot ^ (lr & 15)) << 4)]) = pre[k];
            }
            __syncthreads();   // next chunk ready
        }
    }

    #pragma unroll
    for (int at = 0; at < 2; ++at) {
        const int gi0 = mbase + at * 16 + quad * 4;
        #pragma unroll
        for (int r = 0; r < 4; ++r) {
            float s = rs[at][r];
            s += __shfl_xor(s, 1);
            s += __shfl_xor(s, 2);
            s += __shfl_xor(s, 4);
            s += __shfl_xor(s, 8);
            if (l15 == 0) psum[(size_t)cs * N2 + gi0 + r] = s;
        }
    }
}

// ---- row_finalize v2 (r14, unchanged): one wave per row-pair --------------
__global__ __launch_bounds__(256) void row_finalize(
    const unsigned short* __restrict__ Zb, const float* __restrict__ psum,
    float* __restrict__ out)
{
    const int t = threadIdx.x, wave = t >> 6, lane = t & 63;
    const int half = lane >> 5, l5 = lane & 31;
    const unsigned int* Z32 = (const unsigned int*)Zb;
    const int gw = blockIdx.x * 4 + wave;   // 0..1023
    float accrv = 0.f;

    #pragma unroll 1
    for (int pp = 0; pp < 4; ++pp) {
        const int k = gw * 4 + pp;          // pair 0..4095
        float s = psum[(size_t)l5 * N2 + k + half * NB];
        s += __shfl_xor(s, 1); s += __shfl_xor(s, 2); s += __shfl_xor(s, 4);
        s += __shfl_xor(s, 8); s += __shfl_xor(s, 16);
        unsigned int aw = Z32[(size_t)k * 64 + lane];
        unsigned int bw = Z32[(size_t)(k + NB) * 64 + lane];
        float alo = __uint_as_float(aw << 16), ahi = __uint_as_float(aw & 0xffff0000u);
        float blo = __uint_as_float(bw << 16), bhi = __uint_as_float(bw & 0xffff0000u);
        float d12 = alo * blo + ahi * bhi;
        float d11 = alo * alo + ahi * ahi;
        float d22 = blo * blo + bhi * bhi;
        #pragma unroll
        for (int m = 1; m <= 32; m <<= 1) {
            d12 += __shfl_xor(d12, m);
            d11 += __shfl_xor(d11, m);
            d22 += __shfl_xor(d22, m);
        }
        if (l5 == 0) {
            float dself = half ? d22 : d11;
            accrv += logf(s - fast_exp2(dself)) - d12 * 0.69314718f;
        }
    }
    accrv += __shfl_xor(accrv, 32);   // lane0 += lane32 contribution
    __shared__ float wsr[4];
    if (lane == 0) wsr[wave] = accrv;
    __syncthreads();
    if (t == 0)
        atomicAdd(out, (wsr[0] + wsr[1] + wsr[2] + wsr[3]) * (1.0f / N2));
}

extern "C" void kernel_launch(void* const* d_in, const int* in_sizes, int n_in,
                              void* d_out, int out_size, void* d_ws, size_t ws_size,
                              hipStream_t stream)
{
    const float* h1    = (const float*)d_in[0];
    const float* h2    = (const float*)d_in[1];
    const float* W1    = (const float*)d_in[2];
    const float* b1    = (const float*)d_in[3];
    const float* gamma = (const float*)d_in[4];
    const float* beta  = (const float*)d_in[5];
    const float* W2    = (const float*)d_in[6];
    const float* b2    = (const float*)d_in[7];
    float* out = (float*)d_out;

    float* ws      = (float*)d_ws;
    float* psumc   = ws;                            // 1024 f
    float* psqc    = psumc + 1024;                  // 1024 f
    unsigned short* W1b = (unsigned short*)(psqc + 1024);   // 98304 us
    unsigned short* W2b = W1b + DHID * DIN;         // 65536 us
    float* Y       = (float*)(W2b + DOUT * DHID);   // 8192*512 = 4M f
    float* psum    = Y + (size_t)N2 * DHID;         // 32*8192 f
    unsigned short* Zb = (unsigned short*)(psum + (size_t)NSPLIT * N2); // 1M us
    // total ~20.3 MB

    prep        <<<dim3(161),        256, 0, stream>>>(W1, W2, W1b, W2b, psumc, psqc, out);
    gemm1_mfma  <<<dim3(64, 8),      256, 0, stream>>>(h1, h2, W1b, b1, Y, psumc, psqc);
    gemm2_mfma  <<<dim3(512),        256, 0, stream>>>(Y, W2b, psumc, psqc, gamma, beta, b2, Zb, out + 1);
    sim_mfma    <<<dim3(64, NSPLIT), 256, 0, stream>>>(Zb, psum);
    row_finalize<<<dim3(256),        256, 0, stream>>>(Zb, psum, out);
}

// Round 8
// 137.489 us; speedup vs baseline: 1.2917x; 1.2917x over previous
//
#include <hip/hip_runtime.h>

// SimCLR fused pipeline, round 17.
// r16 post-mortem: reg-prefetch chunking spilled AGAIN (WRITE 168MB, 71us) --
// 3rd confirmation this kernel has no VGPR headroom for in-loop reg staging.
// Calibration from r16: dur = sum(kernels) + 93us harness constant; sim=35us.
// sim's 35us = 4 sequential block-rounds (2048 blocks, 2/CU), each paying
// stage(64KB)->sync->compute serialization; stage traffic 4x redundant.
// r17: ONE variable vs r14 -- sim grid (64,32)->(16,32): each block stages its
// B-slice ONCE then processes 4 row-groups (512 rows/block). 512 blocks =
// exactly 2/CU = single concurrent round; stage traffic 128->32MB; 64-iter
// compute run amortizes stage + hides latency. Inner loop/swizzle/regs
// byte-identical to r12 (proven no-spill). No reg prefetch.
// prep/gemm1/gemm2/row_finalize byte-identical to r14.

#define NB   4096
#define DIN  192
#define DHID 512
#define DOUT 128
#define N2   8192   // 2*NB
#define NSPLIT 32   // sim col-splits; 256 cols per block
#define SIM_ITERS 16

typedef short short8 __attribute__((ext_vector_type(8)));   // 8 bf16 (4 VGPRs)
typedef float floatx4 __attribute__((ext_vector_type(4)));  // MFMA C/D frag

__device__ inline float fast_exp2(float x) {
#if __has_builtin(__builtin_amdgcn_exp2f)
    return __builtin_amdgcn_exp2f(x);
#else
    return exp2f(x);
#endif
}

__device__ inline unsigned short bf16_rne(float x) {
    unsigned int u = __float_as_uint(x);
    return (unsigned short)((u + 0x7fffu + ((u >> 16) & 1u)) >> 16);
}

// ------- prep: convert W1,W2 -> bf16; block 160 zeros psumc/psqc/out -------
__global__ __launch_bounds__(256) void prep(
    const float* __restrict__ W1, const float* __restrict__ W2,
    unsigned short* __restrict__ W1b, unsigned short* __restrict__ W2b,
    float* __restrict__ psumc, float* __restrict__ psqc, float* __restrict__ out)
{
    const int NW1 = DHID * DIN / 4;   // 24576 float4
    const int NW2 = DOUT * DHID / 4;  // 16384 float4
    if (blockIdx.x == 160) {          // zero accumulators
        int t = threadIdx.x;
        for (int i = t; i < 1024; i += 256) { psumc[i] = 0.f; psqc[i] = 0.f; }
        if (t == 0) out[0] = 0.f;
        return;
    }
    int id = blockIdx.x * 256 + threadIdx.x;
    const float* src; unsigned short* dst; int off;
    if (id < NW1)            { src = W1; dst = W1b; off = id; }
    else if (id < NW1 + NW2) { src = W2; dst = W2b; off = id - NW1; }
    else return;
    float4 x = ((const float4*)src)[off];
    unsigned int p0 = bf16_rne(x.x) | ((unsigned int)bf16_rne(x.y) << 16);
    unsigned int p1 = bf16_rne(x.z) | ((unsigned int)bf16_rne(x.w) << 16);
    ((uint2*)dst)[off] = make_uint2(p0, p1);
}

// ------- GEMM1 (r12, unchanged): Y = [h1;h2] @ W1^T + b1, fused BN sums ----
__global__ __launch_bounds__(256) void gemm1_mfma(
    const float* __restrict__ h1, const float* __restrict__ h2,
    const unsigned short* __restrict__ W1b, const float* __restrict__ b1,
    float* __restrict__ Y, float* __restrict__ psumc, float* __restrict__ psqc)
{
    const int t = threadIdx.x;
    const int wave = t >> 6, lane = t & 63;
    const int quad = lane >> 4, l15 = lane & 15;
    const int mb = blockIdx.x;
    const int m0 = mb * 128 + wave * 32;
    const int n0 = blockIdx.y * 64;
    const int v  = (mb >= 32);

    short8 a[2][6];
    #pragma unroll
    for (int mt = 0; mt < 2; ++mt) {
        int row = m0 + mt * 16 + l15;
        const float* hsrc = (row < NB) ? (h1 + (size_t)row * DIN)
                                       : (h2 + (size_t)(row - NB) * DIN);
        #pragma unroll
        for (int kc = 0; kc < 6; ++kc) {
            const float4* p = (const float4*)(hsrc + kc * 32 + quad * 8);
            float4 x0 = p[0], x1 = p[1];
            float xs[8] = {x0.x,x0.y,x0.z,x0.w,x1.x,x1.y,x1.z,x1.w};
            #pragma unroll
            for (int j = 0; j < 8; ++j) a[mt][kc][j] = (short)bf16_rne(xs[j]);
        }
    }

    #pragma unroll
    for (int nt = 0; nt < 4; ++nt) {
        const int col = n0 + nt * 16 + l15;
        const short8* bptr = (const short8*)(W1b + (size_t)col * DIN + quad * 8);
        short8 b[6];
        #pragma unroll
        for (int kc = 0; kc < 6; ++kc) b[kc] = bptr[kc * 4];
        floatx4 acc[2] = {{0.f,0.f,0.f,0.f},{0.f,0.f,0.f,0.f}};
        #pragma unroll
        for (int kc = 0; kc < 6; ++kc)
            #pragma unroll
            for (int mt = 0; mt < 2; ++mt)
                acc[mt] = __builtin_amdgcn_mfma_f32_16x16x32_bf16(a[mt][kc], b[kc], acc[mt], 0,0,0);
        const float bias = b1[col];
        float cs = 0.f, cq = 0.f;
        #pragma unroll
        for (int mt = 0; mt < 2; ++mt)
            #pragma unroll
            for (int reg = 0; reg < 4; ++reg) {
                float y = acc[mt][reg] + bias;
                int row = m0 + mt * 16 + quad * 4 + reg;
                Y[(size_t)row * DHID + col] = y;
                cs += y; cq += y * y;
            }
        cs += __shfl_xor(cs, 16); cs += __shfl_xor(cs, 32);
        cq += __shfl_xor(cq, 16); cq += __shfl_xor(cq, 32);
        if (quad == 0) {
            atomicAdd(psumc + v * DHID + col, cs);
            atomicAdd(psqc  + v * DHID + col, cq);
        }
    }
}

#define ZSCALE 1.6986436f   // sqrt(2*log2(e)); Zb = z*ZSCALE so dot = exp2 arg

// ---- GEMM2 (r12, unchanged): z = relu(bn(Y)) @ W2^T + b2, L2-norm ---------
__global__ __launch_bounds__(256) void gemm2_mfma(
    const float* __restrict__ Y, const unsigned short* __restrict__ W2b,
    const float* __restrict__ psumc, const float* __restrict__ psqc,
    const float* __restrict__ gamma, const float* __restrict__ beta,
    const float* __restrict__ b2,
    unsigned short* __restrict__ Zb, float* __restrict__ outz)
{
    __shared__ float sc_sh[DHID], sh_sh[DHID];
    __shared__ float sq_lds[4][16];
    const int t = threadIdx.x;
    const int wave = t >> 6, lane = t & 63;
    const int quad = lane >> 4, l15 = lane & 15;
    const int mtbase = blockIdx.x * 16;
    const int v = (mtbase >= NB);

    for (int c = t; c < DHID; c += 256) {
        float mean = psumc[v * DHID + c] * (1.0f / NB);
        float var  = psqc [v * DHID + c] * (1.0f / NB) - mean * mean;
        float rstd = rsqrtf(var + 1e-5f);
        float scv = gamma[c] * rstd;
        sc_sh[c] = scv;
        sh_sh[c] = beta[c] - mean * scv;
    }
    __syncthreads();

    const float* yrow = Y + (size_t)(mtbase + l15) * DHID;
    floatx4 acc[2] = {{0.f,0.f,0.f,0.f},{0.f,0.f,0.f,0.f}};
    for (int kc = 0; kc < 16; ++kc) {
        const int k = kc * 32 + quad * 8;
        float4 y0 = *(const float4*)(yrow + k);
        float4 y1 = *(const float4*)(yrow + k + 4);
        float4 s0 = *(const float4*)&sc_sh[k], s1 = *(const float4*)&sc_sh[k + 4];
        float4 h0 = *(const float4*)&sh_sh[k], h1v = *(const float4*)&sh_sh[k + 4];
        float xs[8];
        xs[0] = fmaxf(y0.x * s0.x + h0.x, 0.f);
        xs[1] = fmaxf(y0.y * s0.y + h0.y, 0.f);
        xs[2] = fmaxf(y0.z * s0.z + h0.z, 0.f);
        xs[3] = fmaxf(y0.w * s0.w + h0.w, 0.f);
        xs[4] = fmaxf(y1.x * s1.x + h1v.x, 0.f);
        xs[5] = fmaxf(y1.y * s1.y + h1v.y, 0.f);
        xs[6] = fmaxf(y1.z * s1.z + h1v.z, 0.f);
        xs[7] = fmaxf(y1.w * s1.w + h1v.w, 0.f);
        short8 a;
        #pragma unroll
        for (int j = 0; j < 8; ++j) a[j] = (short)bf16_rne(xs[j]);
        #pragma unroll
        for (int nt = 0; nt < 2; ++nt) {
            const int col = wave * 32 + nt * 16 + l15;
            short8 b = *(const short8*)(W2b + (size_t)col * DHID + k);
            acc[nt] = __builtin_amdgcn_mfma_f32_16x16x32_bf16(a, b, acc[nt], 0,0,0);
        }
    }
    float bias[2];
    #pragma unroll
    for (int nt = 0; nt < 2; ++nt) bias[nt] = b2[wave * 32 + nt * 16 + l15];

    float zv[4][2];
    #pragma unroll
    for (int reg = 0; reg < 4; ++reg) {
        float sq = 0.f;
        #pragma unroll
        for (int nt = 0; nt < 2; ++nt) {
            zv[reg][nt] = acc[nt][reg] + bias[nt];
            sq += zv[reg][nt] * zv[reg][nt];
        }
        sq += __shfl_xor(sq, 1); sq += __shfl_xor(sq, 2);
        sq += __shfl_xor(sq, 4); sq += __shfl_xor(sq, 8);
        if (l15 == 0) sq_lds[wave][quad * 4 + reg] = sq;
    }
    __syncthreads();
    #pragma unroll
    for (int reg = 0; reg < 4; ++reg) {
        float tot = sq_lds[0][quad * 4 + reg] + sq_lds[1][quad * 4 + reg]
                  + sq_lds[2][quad * 4 + reg] + sq_lds[3][quad * 4 + reg];
        float inv = 1.0f / fmaxf(sqrtf(tot), 1e-12f);
        const int row = mtbase + quad * 4 + reg;
        const size_t ob = (size_t)row * DOUT;
        #pragma unroll
        for (int nt = 0; nt < 2; ++nt) {
            const int col = wave * 32 + nt * 16 + l15;
            float z = zv[reg][nt] * inv;
            outz[ob + col] = z;
            Zb[ob + col] = bf16_rne(z * ZSCALE);
        }
    }
}

// ---- sim v5: r12 inner loop, stage ONCE, 4 row-groups per block -----------
// Block stages its 256-col B slice (64KB, 4-bit XOR swizzle) once, then
// processes 512 rows in 4 groups of 128 (32 rows/wave/group; A-frags
// reloaded per group from global -- grid-wide A traffic unchanged).
// 512 blocks = exactly 2/CU -> single concurrent round, no re-staging.
// grid (16, NSPLIT) x 256 thr. LDS 64KB.
__global__ __launch_bounds__(256, 2) void sim_mfma(
    const unsigned short* __restrict__ Zb, float* __restrict__ psum)
{
    __shared__ unsigned char bsh[65536];   // 256 rows x 256 B, swizzled
    const int t = threadIdx.x;
    const int wave = t >> 6, lane = t & 63;
    const int quad = lane >> 4, l15 = lane & 15;
    const int cs = blockIdx.y;                        // 0..NSPLIT-1
    const int cbase = cs * (N2 / NSPLIT);             // 256-col slice

    // ---- stage the whole B slice into LDS (once), swizzled ----
    {
        const uint4* src = (const uint4*)(Zb + (size_t)cbase * DOUT);
        #pragma unroll
        for (int k = 0; k < 16; ++k) {
            int idx = t + k * 256;            // uint4 index 0..4095
            uint4 vv = src[idx];
            int row  = idx >> 4;              // slice row 0..255
            int slot = idx & 15;              // 16B slot within row
            *(uint4*)(bsh + row * 256 + ((slot ^ (row & 15)) << 4)) = vv;
        }
    }
    __syncthreads();   // B slice staged

    #pragma unroll 1
    for (int g = 0; g < 4; ++g) {
        const int mbase = blockIdx.x * 512 + g * 128 + wave * 32;

        // A fragments: 32 rows per wave for this group, K=128 (4 kc)
        short8 a[2][4];
        #pragma unroll
        for (int at = 0; at < 2; ++at) {
            const short8* zra = (const short8*)(Zb + (size_t)(mbase + at * 16 + l15) * DOUT + quad * 8);
            #pragma unroll
            for (int kc = 0; kc < 4; ++kc) a[at][kc] = zra[kc * 4];
        }

        float rs[2][4];
        #pragma unroll
        for (int at = 0; at < 2; ++at)
            #pragma unroll
            for (int r = 0; r < 4; ++r) rs[at][r] = 0.f;

        #pragma unroll 1
        for (int nt = 0; nt < SIM_ITERS; ++nt) {
            const int crow = nt * 16 + l15;
            short8 b[4];
            #pragma unroll
            for (int kc = 0; kc < 4; ++kc) {
                int slot = kc * 4 + quad;
                int boff = crow * 256 + ((slot ^ (crow & 15)) << 4);
                b[kc] = *(const short8*)(bsh + boff);
            }

            floatx4 acc[2] = {{0.f,0.f,0.f,0.f},{0.f,0.f,0.f,0.f}};
            #pragma unroll
            for (int kc = 0; kc < 4; ++kc)
                #pragma unroll
                for (int at = 0; at < 2; ++at)
                    acc[at] = __builtin_amdgcn_mfma_f32_16x16x32_bf16(a[at][kc], b[kc], acc[at], 0, 0, 0);

            #pragma unroll
            for (int at = 0; at < 2; ++at)
                #pragma unroll
                for (int r = 0; r < 4; ++r)
                    rs[at][r] += fast_exp2(acc[at][r]);
        }

        #pragma unroll
        for (int at = 0; at < 2; ++at) {
            const int gi0 = mbase + at * 16 + quad * 4;
            #pragma unroll
            for (int r = 0; r < 4; ++r) {
                float s = rs[at][r];
                s += __shfl_xor(s, 1);
                s += __shfl_xor(s, 2);
                s += __shfl_xor(s, 4);
                s += __shfl_xor(s, 8);
                if (l15 == 0) psum[(size_t)cs * N2 + gi0 + r] = s;
            }
        }
    }
}

// ---- row_finalize v2 (r14, unchanged): one wave per row-pair --------------
__global__ __launch_bounds__(256) void row_finalize(
    const unsigned short* __restrict__ Zb, const float* __restrict__ psum,
    float* __restrict__ out)
{
    const int t = threadIdx.x, wave = t >> 6, lane = t & 63;
    const int half = lane >> 5, l5 = lane & 31;
    const unsigned int* Z32 = (const unsigned int*)Zb;
    const int gw = blockIdx.x * 4 + wave;   // 0..1023
    float accrv = 0.f;

    #pragma unroll 1
    for (int pp = 0; pp < 4; ++pp) {
        const int k = gw * 4 + pp;          // pair 0..4095
        float s = psum[(size_t)l5 * N2 + k + half * NB];
        s += __shfl_xor(s, 1); s += __shfl_xor(s, 2); s += __shfl_xor(s, 4);
        s += __shfl_xor(s, 8); s += __shfl_xor(s, 16);
        unsigned int aw = Z32[(size_t)k * 64 + lane];
        unsigned int bw = Z32[(size_t)(k + NB) * 64 + lane];
        float alo = __uint_as_float(aw << 16), ahi = __uint_as_float(aw & 0xffff0000u);
        float blo = __uint_as_float(bw << 16), bhi = __uint_as_float(bw & 0xffff0000u);
        float d12 = alo * blo + ahi * bhi;
        float d11 = alo * alo + ahi * ahi;
        float d22 = blo * blo + bhi * bhi;
        #pragma unroll
        for (int m = 1; m <= 32; m <<= 1) {
            d12 += __shfl_xor(d12, m);
            d11 += __shfl_xor(d11, m);
            d22 += __shfl_xor(d22, m);
        }
        if (l5 == 0) {
            float dself = half ? d22 : d11;
            accrv += logf(s - fast_exp2(dself)) - d12 * 0.69314718f;
        }
    }
    accrv += __shfl_xor(accrv, 32);   // lane0 += lane32 contribution
    __shared__ float wsr[4];
    if (lane == 0) wsr[wave] = accrv;
    __syncthreads();
    if (t == 0)
        atomicAdd(out, (wsr[0] + wsr[1] + wsr[2] + wsr[3]) * (1.0f / N2));
}

extern "C" void kernel_launch(void* const* d_in, const int* in_sizes, int n_in,
                              void* d_out, int out_size, void* d_ws, size_t ws_size,
                              hipStream_t stream)
{
    const float* h1    = (const float*)d_in[0];
    const float* h2    = (const float*)d_in[1];
    const float* W1    = (const float*)d_in[2];
    const float* b1    = (const float*)d_in[3];
    const float* gamma = (const float*)d_in[4];
    const float* beta  = (const float*)d_in[5];
    const float* W2    = (const float*)d_in[6];
    const float* b2    = (const float*)d_in[7];
    float* out = (float*)d_out;

    float* ws      = (float*)d_ws;
    float* psumc   = ws;                            // 1024 f
    float* psqc    = psumc + 1024;                  // 1024 f
    unsigned short* W1b = (unsigned short*)(psqc + 1024);   // 98304 us
    unsigned short* W2b = W1b + DHID * DIN;         // 65536 us
    float* Y       = (float*)(W2b + DOUT * DHID);   // 8192*512 = 4M f
    float* psum    = Y + (size_t)N2 * DHID;         // 32*8192 f
    unsigned short* Zb = (unsigned short*)(psum + (size_t)NSPLIT * N2); // 1M us
    // total ~20.3 MB

    prep        <<<dim3(161),        256, 0, stream>>>(W1, W2, W1b, W2b, psumc, psqc, out);
    gemm1_mfma  <<<dim3(64, 8),      256, 0, stream>>>(h1, h2, W1b, b1, Y, psumc, psqc);
    gemm2_mfma  <<<dim3(512),        256, 0, stream>>>(Y, W2b, psumc, psqc, gamma, beta, b2, Zb, out + 1);
    sim_mfma    <<<dim3(16, NSPLIT), 256, 0, stream>>>(Zb, psum);
    row_finalize<<<dim3(256),        256, 0, stream>>>(Zb, psum, out);
}